// Round 1
// baseline (198.768 us; speedup 1.0000x reference)
//
#include <hip/hip_runtime.h>
#include <cstdint>
#include <cstddef>

// ---------------------------------------------------------------------------
// SqueezeNet fire module: squeeze(1x1,512->64)+ReLU -> {expand1x1(64->256),
// expand3x3(64->256,pad=1)}+ReLU -> concat.  N=32, H=W=56, fp32 in/out.
// Strategy: fp16 MFMA (16x16x32). S intermediate stored fp16 pixel-major
// [n][p][64] in workspace so expand B-fragments are contiguous 16B loads.
// ---------------------------------------------------------------------------

typedef _Float16 f16;
typedef __attribute__((ext_vector_type(8))) _Float16 f16x8;
typedef __attribute__((ext_vector_type(4))) _Float16 f16x4;
typedef __attribute__((ext_vector_type(4))) float    f32x4;

#define MFMA(a, b, c) __builtin_amdgcn_mfma_f32_16x16x32_f16((a), (b), (c), 0, 0, 0)

#define NIMG 32
#define CIN  512
#define HW   3136     // 56*56
#define W56  56
#define CSQ  64
#define CE   256

// ---------------------------------------------------------------------------
// prep: fp32 -> fp16 weight conversion + W3 repack to [tap][o][i]
// ---------------------------------------------------------------------------
__global__ __launch_bounds__(256) void fire_prep(
    const float* __restrict__ sw, const float* __restrict__ e1w,
    const float* __restrict__ e3w,
    f16* __restrict__ Wsq, f16* __restrict__ W1, f16* __restrict__ W3)
{
    int t = blockIdx.x * 256 + threadIdx.x;
    if (t < CSQ * CIN) {
        Wsq[t] = (f16)sw[t];
    } else if (t < CSQ * CIN + CE * CSQ) {
        int j = t - CSQ * CIN;
        W1[j] = (f16)e1w[j];
    } else {
        int j = t - (CSQ * CIN + CE * CSQ);
        if (j < 9 * CE * CSQ) {
            int tap = j >> 14;            // 16384 = 256*64 per tap
            int rem = j & 16383;
            int o = rem >> 6;
            int i = rem & 63;
            W3[j] = (f16)e3w[(o * CSQ + i) * 9 + tap];
        }
    }
}

// ---------------------------------------------------------------------------
// squeeze: S[n][p][64] = relu(Wsq[64x512] @ x[n][512][p] + b)   (fp16 out)
// block = 4 waves; wave w owns pixels p0+16w..p0+16w+15, all 64 out-ch.
// ---------------------------------------------------------------------------
__global__ __launch_bounds__(256) void fire_squeeze(
    const float* __restrict__ x, const float* __restrict__ sb,
    const f16* __restrict__ Wsq, f16* __restrict__ Sws)
{
    const int tid  = threadIdx.x;
    const int lane = tid & 63, wv = tid >> 6;
    const int i = lane & 15, g = lane >> 4;
    const int n = blockIdx.y;
    const int p = blockIdx.x * 64 + wv * 16 + i;   // this lane's pixel column

    f32x4 acc[4] = {};
    const float* xp = x + (size_t)n * CIN * HW + p;

    #pragma unroll
    for (int kk = 0; kk < 16; ++kk) {
        const int k0 = kk * 32 + g * 8;
        f16x8 b;
        #pragma unroll
        for (int v = 0; v < 8; ++v)
            b[v] = (f16)xp[(size_t)(k0 + v) * HW];
        #pragma unroll
        for (int m = 0; m < 4; ++m) {
            f16x8 a = *(const f16x8*)(Wsq + (16 * m + i) * CIN + k0);
            acc[m] = MFMA(a, b, acc[m]);
        }
    }

    // epilogue: D row = out-ch = 16m + 4g + v ; col = pixel = i
    f16* sp = Sws + ((size_t)n * HW + p) * CSQ;
    #pragma unroll
    for (int m = 0; m < 4; ++m) {
        const int oc = 16 * m + 4 * g;
        const float4 bb = *(const float4*)(sb + oc);
        f16x4 st;
        st[0] = (f16)fmaxf(acc[m][0] + bb.x, 0.f);
        st[1] = (f16)fmaxf(acc[m][1] + bb.y, 0.f);
        st[2] = (f16)fmaxf(acc[m][2] + bb.z, 0.f);
        st[3] = (f16)fmaxf(acc[m][3] + bb.w, 0.f);
        *(f16x4*)(sp + oc) = st;
    }
}

// ---------------------------------------------------------------------------
// expand1x1: out[n][0:256][p] = relu(W1[256x64] @ S + b1)
// block = 4 waves; wave w owns out-ch 64w..64w+63 for pixels p0..p0+63.
// ---------------------------------------------------------------------------
__global__ __launch_bounds__(256) void fire_expand1(
    const f16* __restrict__ Sws, const f16* __restrict__ W1,
    const float* __restrict__ b1, float* __restrict__ out)
{
    const int tid  = threadIdx.x;
    const int lane = tid & 63, wv = tid >> 6;
    const int i = lane & 15, g = lane >> 4;
    const int n  = blockIdx.y;
    const int p0 = blockIdx.x * 64;

    f32x4 acc[4][4] = {};
    #pragma unroll
    for (int kk = 0; kk < 2; ++kk) {
        const int k0 = kk * 32 + g * 8;
        f16x8 b[4];
        #pragma unroll
        for (int c = 0; c < 4; ++c)
            b[c] = *(const f16x8*)(Sws + ((size_t)n * HW + p0 + 16 * c + i) * CSQ + k0);
        #pragma unroll
        for (int m = 0; m < 4; ++m) {
            f16x8 a = *(const f16x8*)(W1 + (64 * wv + 16 * m + i) * CSQ + k0);
            #pragma unroll
            for (int c = 0; c < 4; ++c)
                acc[m][c] = MFMA(a, b[c], acc[m][c]);
        }
    }

    #pragma unroll
    for (int m = 0; m < 4; ++m) {
        const int oc = 64 * wv + 16 * m + 4 * g;
        const float4 bb = *(const float4*)(b1 + oc);
        #pragma unroll
        for (int c = 0; c < 4; ++c) {
            float* op = out + ((size_t)n * 512 + oc) * HW + p0 + 16 * c + i;
            op[0 * (size_t)HW] = fmaxf(acc[m][c][0] + bb.x, 0.f);
            op[1 * (size_t)HW] = fmaxf(acc[m][c][1] + bb.y, 0.f);
            op[2 * (size_t)HW] = fmaxf(acc[m][c][2] + bb.z, 0.f);
            op[3 * (size_t)HW] = fmaxf(acc[m][c][3] + bb.w, 0.f);
        }
    }
}

// ---------------------------------------------------------------------------
// expand3x3: out[n][256:512][p] = relu(conv3x3(S) + b3), implicit GEMM,
// 9 taps x (K=64).  block = 4 waves, tile = 256 out-ch x 112 px (2 rows).
// S tile in LDS: 4 rows x 58 cols (zero-padded borders) x 64 ch, fp16,
// XOR-16 swizzled ( off ^= (q&7)<<4 ) on both write and read.
// ---------------------------------------------------------------------------
__global__ __launch_bounds__(256) void fire_expand3(
    const f16* __restrict__ Sws, const f16* __restrict__ W3,
    const float* __restrict__ b3, float* __restrict__ out)
{
    __shared__ f16 Slds[4 * 58 * 64];   // 29696 B

    const int tid  = threadIdx.x;
    const int lane = tid & 63, wv = tid >> 6;
    const int i = lane & 15, g = lane >> 4;
    const int n  = blockIdx.y;
    const int rb = blockIdx.x;          // 0..27 -> output rows 2rb, 2rb+1
    const int r0 = rb * 2;

    // ---- stage S tile: 232 positions x 8 chunks of 16B = 1856 tasks ----
    #pragma unroll
    for (int it = 0; it < 8; ++it) {
        int task = it * 256 + tid;
        if (task < 232 * 8) {
            int s  = task >> 3, ck = task & 7;
            int tr = s / 58,   tc = s % 58;
            int h = r0 - 1 + tr, w = tc - 1;
            int4 val = make_int4(0, 0, 0, 0);
            if (h >= 0 && h < W56 && w >= 0 && w < W56)
                val = *(const int4*)(Sws + ((size_t)n * HW + h * W56 + w) * CSQ + ck * 8);
            int off = s * 128 + ck * 16;
            off ^= ((s & 7) << 4);
            *(int4*)((char*)Slds + off) = val;
        }
    }
    __syncthreads();

    // per-lane padded-tile position bases for the 7 pixel fragments
    int q0[7];
    #pragma unroll
    for (int c = 0; c < 7; ++c) {
        int pl  = 16 * c + i;                 // 0..111
        int r   = (pl >= W56) ? 1 : 0;
        int col = pl - r * W56;
        q0[c] = r * 58 + col;
    }

    f32x4 acc[4][7] = {};
    for (int dh = 0; dh < 3; ++dh) {
        for (int dw = 0; dw < 3; ++dw) {
            const f16* wtap = W3 + (size_t)(dh * 3 + dw) * CE * CSQ;
            const int toff = dh * 58 + dw;
            #pragma unroll
            for (int kk = 0; kk < 2; ++kk) {
                const int k0 = kk * 32 + g * 8;
                f16x8 b[7];
                #pragma unroll
                for (int c = 0; c < 7; ++c) {
                    int q   = q0[c] + toff;
                    int off = q * 128 + kk * 64 + g * 16;
                    off ^= ((q & 7) << 4);
                    b[c] = *(const f16x8*)((const char*)Slds + off);
                }
                #pragma unroll
                for (int m = 0; m < 4; ++m) {
                    f16x8 a = *(const f16x8*)(wtap + (64 * wv + 16 * m + i) * CSQ + k0);
                    #pragma unroll
                    for (int c = 0; c < 7; ++c)
                        acc[m][c] = MFMA(a, b[c], acc[m][c]);
                }
            }
        }
    }

    // epilogue: out channel = 256 + (64wv + 16m + 4g + v), pixel = rb*112+16c+i
    #pragma unroll
    for (int m = 0; m < 4; ++m) {
        const int ocl = 64 * wv + 16 * m + 4 * g;   // 0..255 within e3
        const float4 bb = *(const float4*)(b3 + ocl);
        #pragma unroll
        for (int c = 0; c < 7; ++c) {
            float* op = out + ((size_t)n * 512 + 256 + ocl) * HW + rb * 112 + 16 * c + i;
            op[0 * (size_t)HW] = fmaxf(acc[m][c][0] + bb.x, 0.f);
            op[1 * (size_t)HW] = fmaxf(acc[m][c][1] + bb.y, 0.f);
            op[2 * (size_t)HW] = fmaxf(acc[m][c][2] + bb.z, 0.f);
            op[3 * (size_t)HW] = fmaxf(acc[m][c][3] + bb.w, 0.f);
        }
    }
}

// ---------------------------------------------------------------------------
extern "C" void kernel_launch(void* const* d_in, const int* in_sizes, int n_in,
                              void* d_out, int out_size, void* d_ws, size_t ws_size,
                              hipStream_t stream)
{
    const float* x  = (const float*)d_in[0];
    const float* sw = (const float*)d_in[1];
    const float* sb = (const float*)d_in[2];
    const float* w1 = (const float*)d_in[3];
    const float* b1 = (const float*)d_in[4];
    const float* w3 = (const float*)d_in[5];
    const float* b3 = (const float*)d_in[6];
    float* out = (float*)d_out;

    // workspace layout (fp16): S [32][3136][64], Wsq [64][512],
    // W1 [256][64], W3 [9][256][64]
    f16* Sws = (f16*)d_ws;
    f16* Wsq = Sws + (size_t)NIMG * HW * CSQ;
    f16* W1b = Wsq + CSQ * CIN;
    f16* W3b = W1b + CE * CSQ;

    fire_prep<<<768, 256, 0, stream>>>(sw, w1, w3, Wsq, W1b, W3b);
    fire_squeeze<<<dim3(49, 32), 256, 0, stream>>>(x, sb, Wsq, Sws);
    fire_expand1<<<dim3(49, 32), 256, 0, stream>>>(Sws, W1b, b1, out);
    fire_expand3<<<dim3(28, 32), 256, 0, stream>>>(Sws, W3b, b3, out);
}

// Round 2
// 175.126 us; speedup vs baseline: 1.1350x; 1.1350x over previous
//
#include <hip/hip_runtime.h>
#include <cstdint>
#include <cstddef>

// ---------------------------------------------------------------------------
// SqueezeNet fire module: squeeze(1x1,512->64)+ReLU -> {expand1x1(64->256),
// expand3x3(64->256,pad=1)}+ReLU -> concat.  N=32, H=W=56, fp32 in/out.
// fp16 MFMA (16x16x32). S intermediate fp16 pixel-major [n][p][64].
// R2: squeeze rewritten with fully-coalesced float4 x-loads feeding 4
// interleaved-pixel B-fragments (px = p0 + 4*i + c) -- no strided gathers.
// ---------------------------------------------------------------------------

typedef _Float16 f16;
typedef __attribute__((ext_vector_type(8))) _Float16 f16x8;
typedef __attribute__((ext_vector_type(4))) _Float16 f16x4;
typedef __attribute__((ext_vector_type(4))) float    f32x4;

#define MFMA(a, b, c) __builtin_amdgcn_mfma_f32_16x16x32_f16((a), (b), (c), 0, 0, 0)

#define NIMG 32
#define CIN  512
#define HW   3136     // 56*56
#define W56  56
#define CSQ  64
#define CE   256

// ---------------------------------------------------------------------------
// prep: fp32 -> fp16 weight conversion + W3 repack to [tap][o][i]
// ---------------------------------------------------------------------------
__global__ __launch_bounds__(256) void fire_prep(
    const float* __restrict__ sw, const float* __restrict__ e1w,
    const float* __restrict__ e3w,
    f16* __restrict__ Wsq, f16* __restrict__ W1, f16* __restrict__ W3)
{
    int t = blockIdx.x * 256 + threadIdx.x;
    if (t < CSQ * CIN) {
        Wsq[t] = (f16)sw[t];
    } else if (t < CSQ * CIN + CE * CSQ) {
        int j = t - CSQ * CIN;
        W1[j] = (f16)e1w[j];
    } else {
        int j = t - (CSQ * CIN + CE * CSQ);
        if (j < 9 * CE * CSQ) {
            int tap = j >> 14;            // 16384 = 256*64 per tap
            int rem = j & 16383;
            int o = rem >> 6;
            int i = rem & 63;
            W3[j] = (f16)e3w[(o * CSQ + i) * 9 + tap];
        }
    }
}

// ---------------------------------------------------------------------------
// squeeze v2: S[n][p][64] = relu(Wsq[64x512] @ x[n][512][p] + b)  (fp16 out)
// wave-tile = 64 px x 64 oc.  1568 wave-tiles = 392 blocks x 4 waves.
// B-fragment column c maps to pixel p0 + 4*i + c, so one float4 global load
// (16 lanes x 16B = 256B contiguous) supplies element v of fragments c=0..3.
// ---------------------------------------------------------------------------
__global__ __launch_bounds__(256) void fire_squeeze2(
    const float* __restrict__ x, const float* __restrict__ sb,
    const f16* __restrict__ Wsq, f16* __restrict__ Sws)
{
    const int tid  = threadIdx.x;
    const int lane = tid & 63, wv = tid >> 6;
    const int i = lane & 15, g = lane >> 4;
    const int w  = blockIdx.x * 4 + wv;     // 0..1567
    const int n  = w / 49;
    const int p0 = (w % 49) * 64;

    const float* xp = x + (size_t)n * CIN * HW + p0 + 4 * i;

    f32x4 acc[4][4] = {};
    #pragma unroll
    for (int kk = 0; kk < 16; ++kk) {
        const int k0 = kk * 32 + g * 8;
        f16x8 b[4];
        #pragma unroll
        for (int v = 0; v < 8; ++v) {
            float4 q = *(const float4*)(xp + (size_t)(k0 + v) * HW);
            b[0][v] = (f16)q.x;
            b[1][v] = (f16)q.y;
            b[2][v] = (f16)q.z;
            b[3][v] = (f16)q.w;
        }
        #pragma unroll
        for (int m = 0; m < 4; ++m) {
            f16x8 a = *(const f16x8*)(Wsq + (16 * m + i) * CIN + k0);
            #pragma unroll
            for (int c = 0; c < 4; ++c)
                acc[m][c] = MFMA(a, b[c], acc[m][c]);
        }
    }

    // D: row = oc = 16m + 4g + v, col = i -> pixel p0 + 4i + c
    #pragma unroll
    for (int m = 0; m < 4; ++m) {
        const int oc = 16 * m + 4 * g;
        const float4 bb = *(const float4*)(sb + oc);
        #pragma unroll
        for (int c = 0; c < 4; ++c) {
            const int px = p0 + 4 * i + c;
            f16x4 st;
            st[0] = (f16)fmaxf(acc[m][c][0] + bb.x, 0.f);
            st[1] = (f16)fmaxf(acc[m][c][1] + bb.y, 0.f);
            st[2] = (f16)fmaxf(acc[m][c][2] + bb.z, 0.f);
            st[3] = (f16)fmaxf(acc[m][c][3] + bb.w, 0.f);
            *(f16x4*)(Sws + ((size_t)n * HW + px) * CSQ + oc) = st;
        }
    }
}

// ---------------------------------------------------------------------------
// expand1x1: out[n][0:256][p] = relu(W1[256x64] @ S + b1)
// block = 4 waves; wave w owns out-ch 64w..64w+63 for pixels p0..p0+63.
// ---------------------------------------------------------------------------
__global__ __launch_bounds__(256) void fire_expand1(
    const f16* __restrict__ Sws, const f16* __restrict__ W1,
    const float* __restrict__ b1, float* __restrict__ out)
{
    const int tid  = threadIdx.x;
    const int lane = tid & 63, wv = tid >> 6;
    const int i = lane & 15, g = lane >> 4;
    const int n  = blockIdx.y;
    const int p0 = blockIdx.x * 64;

    f32x4 acc[4][4] = {};
    #pragma unroll
    for (int kk = 0; kk < 2; ++kk) {
        const int k0 = kk * 32 + g * 8;
        f16x8 b[4];
        #pragma unroll
        for (int c = 0; c < 4; ++c)
            b[c] = *(const f16x8*)(Sws + ((size_t)n * HW + p0 + 16 * c + i) * CSQ + k0);
        #pragma unroll
        for (int m = 0; m < 4; ++m) {
            f16x8 a = *(const f16x8*)(W1 + (64 * wv + 16 * m + i) * CSQ + k0);
            #pragma unroll
            for (int c = 0; c < 4; ++c)
                acc[m][c] = MFMA(a, b[c], acc[m][c]);
        }
    }

    #pragma unroll
    for (int m = 0; m < 4; ++m) {
        const int oc = 64 * wv + 16 * m + 4 * g;
        const float4 bb = *(const float4*)(b1 + oc);
        #pragma unroll
        for (int c = 0; c < 4; ++c) {
            float* op = out + ((size_t)n * 512 + oc) * HW + p0 + 16 * c + i;
            op[0 * (size_t)HW] = fmaxf(acc[m][c][0] + bb.x, 0.f);
            op[1 * (size_t)HW] = fmaxf(acc[m][c][1] + bb.y, 0.f);
            op[2 * (size_t)HW] = fmaxf(acc[m][c][2] + bb.z, 0.f);
            op[3 * (size_t)HW] = fmaxf(acc[m][c][3] + bb.w, 0.f);
        }
    }
}

// ---------------------------------------------------------------------------
// expand3x3: out[n][256:512][p] = relu(conv3x3(S) + b3), implicit GEMM,
// 9 taps x (K=64).  block = 4 waves, tile = 256 out-ch x 112 px (2 rows).
// S tile in LDS: 4 rows x 58 cols (zero-padded borders) x 64 ch, fp16,
// XOR-16 swizzled ( off ^= (q&7)<<4 ) on both write and read.
// ---------------------------------------------------------------------------
__global__ __launch_bounds__(256) void fire_expand3(
    const f16* __restrict__ Sws, const f16* __restrict__ W3,
    const float* __restrict__ b3, float* __restrict__ out)
{
    __shared__ f16 Slds[4 * 58 * 64];   // 29696 B

    const int tid  = threadIdx.x;
    const int lane = tid & 63, wv = tid >> 6;
    const int i = lane & 15, g = lane >> 4;
    const int n  = blockIdx.y;
    const int rb = blockIdx.x;          // 0..27 -> output rows 2rb, 2rb+1
    const int r0 = rb * 2;

    // ---- stage S tile: 232 positions x 8 chunks of 16B = 1856 tasks ----
    #pragma unroll
    for (int it = 0; it < 8; ++it) {
        int task = it * 256 + tid;
        if (task < 232 * 8) {
            int s  = task >> 3, ck = task & 7;
            int tr = s / 58,   tc = s % 58;
            int h = r0 - 1 + tr, w = tc - 1;
            int4 val = make_int4(0, 0, 0, 0);
            if (h >= 0 && h < W56 && w >= 0 && w < W56)
                val = *(const int4*)(Sws + ((size_t)n * HW + h * W56 + w) * CSQ + ck * 8);
            int off = s * 128 + ck * 16;
            off ^= ((s & 7) << 4);
            *(int4*)((char*)Slds + off) = val;
        }
    }
    __syncthreads();

    // per-lane padded-tile position bases for the 7 pixel fragments
    int q0[7];
    #pragma unroll
    for (int c = 0; c < 7; ++c) {
        int pl  = 16 * c + i;                 // 0..111
        int r   = (pl >= W56) ? 1 : 0;
        int col = pl - r * W56;
        q0[c] = r * 58 + col;
    }

    f32x4 acc[4][7] = {};
    for (int dh = 0; dh < 3; ++dh) {
        for (int dw = 0; dw < 3; ++dw) {
            const f16* wtap = W3 + (size_t)(dh * 3 + dw) * CE * CSQ;
            const int toff = dh * 58 + dw;
            #pragma unroll
            for (int kk = 0; kk < 2; ++kk) {
                const int k0 = kk * 32 + g * 8;
                f16x8 b[7];
                #pragma unroll
                for (int c = 0; c < 7; ++c) {
                    int q   = q0[c] + toff;
                    int off = q * 128 + kk * 64 + g * 16;
                    off ^= ((q & 7) << 4);
                    b[c] = *(const f16x8*)((const char*)Slds + off);
                }
                #pragma unroll
                for (int m = 0; m < 4; ++m) {
                    f16x8 a = *(const f16x8*)(wtap + (64 * wv + 16 * m + i) * CSQ + k0);
                    #pragma unroll
                    for (int c = 0; c < 7; ++c)
                        acc[m][c] = MFMA(a, b[c], acc[m][c]);
                }
            }
        }
    }

    // epilogue: out channel = 256 + (64wv + 16m + 4g + v), pixel = rb*112+16c+i
    #pragma unroll
    for (int m = 0; m < 4; ++m) {
        const int ocl = 64 * wv + 16 * m + 4 * g;   // 0..255 within e3
        const float4 bb = *(const float4*)(b3 + ocl);
        #pragma unroll
        for (int c = 0; c < 7; ++c) {
            float* op = out + ((size_t)n * 512 + 256 + ocl) * HW + rb * 112 + 16 * c + i;
            op[0 * (size_t)HW] = fmaxf(acc[m][c][0] + bb.x, 0.f);
            op[1 * (size_t)HW] = fmaxf(acc[m][c][1] + bb.y, 0.f);
            op[2 * (size_t)HW] = fmaxf(acc[m][c][2] + bb.z, 0.f);
            op[3 * (size_t)HW] = fmaxf(acc[m][c][3] + bb.w, 0.f);
        }
    }
}

// ---------------------------------------------------------------------------
extern "C" void kernel_launch(void* const* d_in, const int* in_sizes, int n_in,
                              void* d_out, int out_size, void* d_ws, size_t ws_size,
                              hipStream_t stream)
{
    const float* x  = (const float*)d_in[0];
    const float* sw = (const float*)d_in[1];
    const float* sb = (const float*)d_in[2];
    const float* w1 = (const float*)d_in[3];
    const float* b1 = (const float*)d_in[4];
    const float* w3 = (const float*)d_in[5];
    const float* b3 = (const float*)d_in[6];
    float* out = (float*)d_out;

    // workspace layout (fp16): S [32][3136][64], Wsq [64][512],
    // W1 [256][64], W3 [9][256][64]
    f16* Sws = (f16*)d_ws;
    f16* Wsq = Sws + (size_t)NIMG * HW * CSQ;
    f16* W1b = Wsq + CSQ * CIN;
    f16* W3b = W1b + CE * CSQ;

    fire_prep<<<768, 256, 0, stream>>>(sw, w1, w3, Wsq, W1b, W3b);
    fire_squeeze2<<<392, 256, 0, stream>>>(x, sb, Wsq, Sws);
    fire_expand1<<<dim3(49, 32), 256, 0, stream>>>(Sws, W1b, b1, out);
    fire_expand3<<<dim3(28, 32), 256, 0, stream>>>(Sws, W3b, b3, out);
}